// Round 8
// baseline (581.365 us; speedup 1.0000x reference)
//
#include <hip/hip_runtime.h>
#include <stdint.h>

typedef float f32x4 __attribute__((ext_vector_type(4)));
typedef float f32x2 __attribute__((ext_vector_type(2)));
typedef short bf16x8 __attribute__((ext_vector_type(8)));
typedef uint32_t u32x4 __attribute__((ext_vector_type(4)));

__device__ __forceinline__ uint32_t bf16_rne(float f) {
  uint32_t x = __float_as_uint(f);
  return (x + 0x7FFFu + ((x >> 16) & 1u)) >> 16;
}

// LDS-only barrier: waits this wave's DS ops, does NOT drain vmcnt.
__device__ __forceinline__ void ldsbar() {
  asm volatile("s_waitcnt lgkmcnt(0)\n\ts_barrier" ::: "memory");
}

// ---------------- kernel 0: cast x (f32) -> bf16 ----------------
__global__ void cast_x_kernel(const float* __restrict__ x,
                              uint32_t* __restrict__ xb, int n2) {
  int i = blockIdx.x * 256 + threadIdx.x;
  if (i >= n2) return;
  f32x2 v = *(const f32x2*)(x + 2 * i);
  xb[i] = bf16_rne(v[0]) | (bf16_rne(v[1]) << 16);
}

// ------------- fully-fused 3-layer MLP, one class per block -------------
// Block = class c, M=256 full batch (8 waves x 32 rows), N in 8 chunks of 64.
// W1,W2 each streamed from HBM EXACTLY ONCE (1.34 GB total).
// h1 entirely in REGISTERS: h[8][2][2] bf16x8 = 128 VGPR/lane, built via a
// wave-private LDS transpose bounce per chunk. Layer-3 W3-dot fused.
// __launch_bounds__(512,1): R7 showed (512,2) caps VGPR at 128 -> 478 MB of
// scratch spills. (512,1) -> 256-VGPR cap, fits the ~246 live set.
// W stream: 3-deep reg rotation -> v_cvt_pk_bf16_f32 -> swizzled
// ds_write_b128, double-buffered; barriers lgkm-only; vmcnt monotone.
// LDS: 0/8K B-dbuf | 16K b1 | 18K b2 | 20K W3 | 24K b3 | 32K+w*8K transpose.
__global__ __launch_bounds__(512, 1) void fused_mlp(
    const uint16_t* __restrict__ xb, const float* __restrict__ W1,
    const float* __restrict__ b1, const float* __restrict__ W2,
    const float* __restrict__ b2, const float* __restrict__ W3,
    const float* __restrict__ b3, float* __restrict__ out) {
  __shared__ uint8_t smem[98304];

  const int tid = threadIdx.x;
  const int bid = blockIdx.x;
  const int c = ((bid & 7) << 6) | (bid >> 3);  // bijective XCD swizzle

  const float* W1c = W1 + (size_t)c * (768 * 512);
  const float* W2c = W2 + (size_t)c * (512 * 512);

  const int l = tid & 63, w = tid >> 6;
  const int lr = l & 15, lg = l >> 4;

  // stage per-class small tensors (oldest in vmcnt stream)
  ((float*)(smem + 16384))[tid] = b1[(size_t)c * 512 + tid];
  ((float*)(smem + 18432))[tid] = b2[(size_t)c * 512 + tid];
  ((float*)(smem + 20480))[tid] = W3[(size_t)c * 1024 + tid];
  ((float*)(smem + 20480))[tid + 512] = W3[(size_t)c * 1024 + 512 + tid];
  if (tid < 2) ((float*)(smem + 24576))[tid] = b3[c * 2 + tid];

  const uint16_t* Ap = xb + (size_t)(w * 32 + lr) * 768 + lg * 8;
  uint8_t* T = smem + 32768 + w * 8192;  // wave-private transpose tile
  const float* b1s = (const float*)(smem + 16384);
  const float* b2s = (const float*)(smem + 18432);
  const f32x2* w3s = (const f32x2*)(smem + 20480);

  f32x4 acc[2][4];
#pragma unroll
  for (int i = 0; i < 2; i++)
#pragma unroll
    for (int j = 0; j < 4; j++) acc[i][j] = {0.f, 0.f, 0.f, 0.f};

  bf16x8 h[8][2][2];  // [k-chunk][kk][mf] -- all indices static

  auto loadB = [&](const float* Wc, int so, int ts, float* g) {
    const float* p = Wc + (size_t)(ts * 64 + w * 8) * 512 + so * 64 + l;
#pragma unroll
    for (int r = 0; r < 8; r++) g[r] = p[(size_t)r * 512];
  };
  auto loadA = [&](int ts, bf16x8* as) {
#pragma unroll
    for (int kk = 0; kk < 2; ++kk)
#pragma unroll
      for (int mf = 0; mf < 2; mf++)
        as[kk * 2 + mf] =
            *(const bf16x8*)(Ap + ts * 64 + kk * 32 + (size_t)mf * 16 * 768);
  };
  auto writeB = [&](const float* g, int buf) {
    uint32_t p0, p1, p2, p3;
    asm("v_cvt_pk_bf16_f32 %0, %1, %2" : "=v"(p0) : "v"(g[0]), "v"(g[1]));
    asm("v_cvt_pk_bf16_f32 %0, %1, %2" : "=v"(p1) : "v"(g[2]), "v"(g[3]));
    asm("v_cvt_pk_bf16_f32 %0, %1, %2" : "=v"(p2) : "v"(g[4]), "v"(g[5]));
    asm("v_cvt_pk_bf16_f32 %0, %1, %2" : "=v"(p3) : "v"(g[6]), "v"(g[7]));
    u32x4 p = {p0, p1, p2, p3};
    *(u32x4*)(smem + buf * 8192 + l * 128 + ((w ^ (l & 7)) << 4)) = p;
  };
  auto compB = [&](const uint8_t* s, int kk, bf16x8* b) {
    const int kx = ((lg * 16) ^ ((lr & 7) << 4)) ^ (kk << 6);
#pragma unroll
    for (int nf = 0; nf < 4; nf++)
      b[nf] = *(const bf16x8*)(s + (nf * 16 + lr) * 128 + kx);
  };

  float g[3][8];
  bf16x8 a[2][4];

  // =================== layer 1: 8 chunks x 12 K-steps ===================
  loadB(W1c, 0, 0, g[0]);
  loadB(W1c, 0, 1, g[1]);
  loadA(0, a[0]);
  loadB(W1c, 0, 2, g[2]);
  loadA(1, a[1]);
  writeB(g[0], 0);
  ldsbar();

#pragma unroll
  for (int so = 0; so < 8; ++so) {
#pragma unroll
    for (int k = 0; k < 12; ++k) {
      const int t = so * 12 + k;
      {  // comp
        const uint8_t* s = smem + (t & 1) * 8192;
#pragma unroll
        for (int kk = 0; kk < 2; ++kk) {
          bf16x8 b[4];
          compB(s, kk, b);
#pragma unroll
          for (int mf = 0; mf < 2; mf++)
#pragma unroll
            for (int nf = 0; nf < 4; nf++)
              acc[mf][nf] = __builtin_amdgcn_mfma_f32_16x16x32_bf16(
                  a[t & 1][kk * 2 + mf], b[nf], acc[mf][nf], 0, 0, 0);
        }
      }
      if (k == 11) {  // epilogue: bias+relu -> transpose bounce -> h regs
#pragma unroll
        for (int mf = 0; mf < 2; mf++)
#pragma unroll
          for (int nf = 0; nf < 4; nf++) {
            float bv = b1s[so * 64 + nf * 16 + lr];
#pragma unroll
            for (int r = 0; r < 4; r++) {
              int m = mf * 16 + lg * 4 + r;
              float v = fmaxf(acc[mf][nf][r] + bv, 0.f);
              *(uint16_t*)(T + m * 128 +
                           (((nf * 16 + lr) * 2) ^ ((m & 7) << 4))) =
                  (uint16_t)bf16_rne(v);
            }
            acc[mf][nf] = f32x4{0.f, 0.f, 0.f, 0.f};
          }
#pragma unroll
        for (int kk = 0; kk < 2; kk++)
#pragma unroll
          for (int mf = 0; mf < 2; mf++) {
            int m = mf * 16 + lr;
            h[so][kk][mf] = *(const bf16x8*)(
                T + m * 128 + ((kk * 64 + lg * 16) ^ ((m & 7) << 4)));
          }
      }
      const bool last = (t == 95);
      if (!last) writeB(g[(t + 1) % 3], (t + 1) & 1);
      if (t + 2 < 96) loadA((t + 2) % 12, a[t & 1]);
      if (t + 3 < 96) loadB(W1c, (t + 3) / 12, (t + 3) % 12, g[t % 3]);
      if (!last) ldsbar();
    }
  }

  // ============ layer 2 + fused layer 3: 8 chunks x 8 K-steps ============
  float s0[2][4], s1[2][4];
#pragma unroll
  for (int mf = 0; mf < 2; mf++)
#pragma unroll
    for (int r = 0; r < 4; r++) {
      s0[mf][r] = 0.f;
      s1[mf][r] = 0.f;
    }

  loadB(W2c, 0, 0, g[0]);
  loadB(W2c, 0, 1, g[1]);
  loadB(W2c, 0, 2, g[2]);
  writeB(g[0], 0);
  ldsbar();

#pragma unroll
  for (int so = 0; so < 8; ++so) {
#pragma unroll
    for (int k = 0; k < 8; ++k) {
      const int t = so * 8 + k;
      {  // comp: A from h regs
        const uint8_t* s = smem + (t & 1) * 8192;
#pragma unroll
        for (int kk = 0; kk < 2; ++kk) {
          bf16x8 b[4];
          compB(s, kk, b);
#pragma unroll
          for (int mf = 0; mf < 2; mf++)
#pragma unroll
            for (int nf = 0; nf < 4; nf++)
              acc[mf][nf] = __builtin_amdgcn_mfma_f32_16x16x32_bf16(
                  h[k][kk][mf], b[nf], acc[mf][nf], 0, 0, 0);
        }
      }
      if (k == 7) {  // epilogue: bias+relu -> W3 dot accumulate
#pragma unroll
        for (int mf = 0; mf < 2; mf++)
#pragma unroll
          for (int nf = 0; nf < 4; nf++) {
            float bv = b2s[so * 64 + nf * 16 + lr];
            f32x2 wp = w3s[so * 64 + nf * 16 + lr];
#pragma unroll
            for (int r = 0; r < 4; r++) {
              float v = fmaxf(acc[mf][nf][r] + bv, 0.f);
              s0[mf][r] += v * wp[0];
              s1[mf][r] += v * wp[1];
            }
            acc[mf][nf] = f32x4{0.f, 0.f, 0.f, 0.f};
          }
      }
      const bool last = (t == 63);
      if (!last) writeB(g[(t + 1) % 3], (t + 1) & 1);
      if (t + 3 < 64) loadB(W2c, (t + 3) / 8, (t + 3) % 8, g[t % 3]);
      if (!last) ldsbar();
    }
  }

  // ---------------- final: shfl-reduce over 16 lanes, store ----------------
  f32x2 b3v = *(const f32x2*)(smem + 24576);
#pragma unroll
  for (int mf = 0; mf < 2; mf++)
#pragma unroll
    for (int r = 0; r < 4; r++) {
      float t0 = s0[mf][r], t1 = s1[mf][r];
#pragma unroll
      for (int d = 1; d < 16; d <<= 1) {
        t0 += __shfl_xor(t0, d);
        t1 += __shfl_xor(t1, d);
      }
      if (lr == 0) {
        int row = w * 32 + mf * 16 + lg * 4 + r;
        *(f32x2*)(out + ((size_t)row * 512 + c) * 2) =
            f32x2{t0 + b3v[0], t1 + b3v[1]};
      }
    }
}

extern "C" void kernel_launch(void* const* d_in, const int* in_sizes, int n_in,
                              void* d_out, int out_size, void* d_ws,
                              size_t ws_size, hipStream_t stream) {
  const float* x = (const float*)d_in[0];
  const float* W1 = (const float*)d_in[1];
  const float* b1 = (const float*)d_in[2];
  const float* W2 = (const float*)d_in[3];
  const float* b2 = (const float*)d_in[4];
  const float* W3 = (const float*)d_in[5];
  const float* b3 = (const float*)d_in[6];
  float* out = (float*)d_out;

  uint8_t* ws = (uint8_t*)d_ws;
  if (ws_size < 393216) return;
  uint32_t* xb = (uint32_t*)ws;

  cast_x_kernel<<<dim3(384), dim3(256), 0, stream>>>(x, xb, 98304);
  fused_mlp<<<dim3(512), dim3(512), 0, stream>>>(
      (const uint16_t*)xb, W1, b1, W2, b2, W3, b3, out);
}

// Round 9
// 538.546 us; speedup vs baseline: 1.0795x; 1.0795x over previous
//
#include <hip/hip_runtime.h>
#include <stdint.h>

typedef float f32x4 __attribute__((ext_vector_type(4)));
typedef float f32x2 __attribute__((ext_vector_type(2)));
typedef short bf16x8 __attribute__((ext_vector_type(8)));
typedef uint32_t u32x4 __attribute__((ext_vector_type(4)));

__device__ __forceinline__ uint32_t bf16_rne(float f) {
  uint32_t x = __float_as_uint(f);
  return (x + 0x7FFFu + ((x >> 16) & 1u)) >> 16;
}

// LDS-only barrier: waits this wave's DS ops, does NOT drain vmcnt.
__device__ __forceinline__ void ldsbar() {
  asm volatile("s_waitcnt lgkmcnt(0)\n\ts_barrier" ::: "memory");
}

// ---------------- kernel 0: cast x (f32) -> bf16 ----------------
__global__ void cast_x_kernel(const float* __restrict__ x,
                              uint32_t* __restrict__ xb, int n2) {
  int i = blockIdx.x * 256 + threadIdx.x;
  if (i >= n2) return;
  f32x2 v = *(const f32x2*)(x + 2 * i);
  xb[i] = bf16_rne(v[0]) | (bf16_rne(v[1]) << 16);
}

// ------------- fully-fused 3-layer MLP, one class per block -------------
// Block = class c, M=256 (8 waves x 32 rows). W1,W2 streamed ONCE.
// h1 split: k-chunks 0-3 pinned in AGPRs (64 regs, accvgpr asm) via the
// wave-private LDS transpose bounce; k-chunks 4-7 in LDS (128 KB, swizzled
// C-layout write -> A-frag read, R5-proven pair). Keeps VGPR-class <=128
// (the hard cap for 512-thr blocks) -> no scratch spills.
// LDS: 0/8K B-dbuf | 16K b1 | 18K b2 | 20K W3 | 24K b3 |
//      28K h1-LDS j=0..3 (4x32K; T-bounce 32K overlaps j=0, time-disjoint).
__global__ __launch_bounds__(512, 1) void fused_mlp(
    const uint16_t* __restrict__ xb, const float* __restrict__ W1,
    const float* __restrict__ b1, const float* __restrict__ W2,
    const float* __restrict__ b2, const float* __restrict__ W3,
    const float* __restrict__ b3, float* __restrict__ out) {
  constexpr int HOFF = 28672;
  __shared__ uint8_t smem[159744];

  const int tid = threadIdx.x;
  const int bid = blockIdx.x;
  const int c = ((bid & 7) << 6) | (bid >> 3);  // bijective XCD swizzle

  const float* W1c = W1 + (size_t)c * (768 * 512);
  const float* W2c = W2 + (size_t)c * (512 * 512);

  const int l = tid & 63, w = tid >> 6;
  const int lr = l & 15, lg = l >> 4;

  // stage per-class small tensors (oldest in vmcnt stream)
  ((float*)(smem + 16384))[tid] = b1[(size_t)c * 512 + tid];
  ((float*)(smem + 18432))[tid] = b2[(size_t)c * 512 + tid];
  ((float*)(smem + 20480))[tid] = W3[(size_t)c * 1024 + tid];
  ((float*)(smem + 20480))[tid + 512] = W3[(size_t)c * 1024 + 512 + tid];
  if (tid < 2) ((float*)(smem + 24576))[tid] = b3[c * 2 + tid];

  const uint16_t* Ap = xb + (size_t)(w * 32 + lr) * 768 + lg * 8;
  uint8_t* T = smem + HOFF + w * 4096;  // transpose bounce (so<4 only)
  const float* b1s = (const float*)(smem + 16384);
  const float* b2s = (const float*)(smem + 18432);
  const f32x2* w3s = (const f32x2*)(smem + 20480);

  f32x4 acc[2][4];
#pragma unroll
  for (int i = 0; i < 2; i++)
#pragma unroll
    for (int j = 0; j < 4; j++) acc[i][j] = {0.f, 0.f, 0.f, 0.f};

  uint32_t ha[4][2][2][4];  // AGPR-pinned h1 k-chunks 0..3 (static idx only)

  auto loadB = [&](const float* Wc, int so, int ts, float* g) {
    const float* p = Wc + (size_t)(ts * 64 + w * 8) * 512 + so * 64 + l;
#pragma unroll
    for (int r = 0; r < 8; r++) g[r] = p[(size_t)r * 512];
  };
  auto loadA = [&](int ts, bf16x8* as) {
#pragma unroll
    for (int kk = 0; kk < 2; ++kk)
#pragma unroll
      for (int mf = 0; mf < 2; mf++)
        as[kk * 2 + mf] =
            *(const bf16x8*)(Ap + ts * 64 + kk * 32 + (size_t)mf * 16 * 768);
  };
  auto writeB = [&](const float* g, int buf) {
    uint32_t p0, p1, p2, p3;
    asm("v_cvt_pk_bf16_f32 %0, %1, %2" : "=v"(p0) : "v"(g[0]), "v"(g[1]));
    asm("v_cvt_pk_bf16_f32 %0, %1, %2" : "=v"(p1) : "v"(g[2]), "v"(g[3]));
    asm("v_cvt_pk_bf16_f32 %0, %1, %2" : "=v"(p2) : "v"(g[4]), "v"(g[5]));
    asm("v_cvt_pk_bf16_f32 %0, %1, %2" : "=v"(p3) : "v"(g[6]), "v"(g[7]));
    u32x4 p = {p0, p1, p2, p3};
    *(u32x4*)(smem + buf * 8192 + l * 128 + ((w ^ (l & 7)) << 4)) = p;
  };
  auto compB = [&](const uint8_t* s, int kk, bf16x8* b) {
    const int kx = ((lg * 16) ^ ((lr & 7) << 4)) ^ (kk << 6);
#pragma unroll
    for (int nf = 0; nf < 4; nf++)
      b[nf] = *(const bf16x8*)(s + (nf * 16 + lr) * 128 + kx);
  };

  float g[3][8];
  bf16x8 a[2][4];

  // =================== layer 1: 8 chunks x 12 K-steps ===================
  loadB(W1c, 0, 0, g[0]);
  loadB(W1c, 0, 1, g[1]);
  loadA(0, a[0]);
  loadB(W1c, 0, 2, g[2]);
  loadA(1, a[1]);
  writeB(g[0], 0);
  ldsbar();

#pragma unroll
  for (int so = 0; so < 8; ++so) {
#pragma unroll
    for (int k = 0; k < 12; ++k) {
      const int t = so * 12 + k;
      {  // comp
        const uint8_t* s = smem + (t & 1) * 8192;
#pragma unroll
        for (int kk = 0; kk < 2; ++kk) {
          bf16x8 b[4];
          compB(s, kk, b);
#pragma unroll
          for (int mf = 0; mf < 2; mf++)
#pragma unroll
            for (int nf = 0; nf < 4; nf++)
              acc[mf][nf] = __builtin_amdgcn_mfma_f32_16x16x32_bf16(
                  a[t & 1][kk * 2 + mf], b[nf], acc[mf][nf], 0, 0, 0);
        }
      }
      if (k == 11) {
        if (so < 4) {  // bias+relu -> T bounce -> AGPR pin
#pragma unroll
          for (int mf = 0; mf < 2; mf++)
#pragma unroll
            for (int nf = 0; nf < 4; nf++) {
              float bv = b1s[so * 64 + nf * 16 + lr];
#pragma unroll
              for (int r = 0; r < 4; r++) {
                int m = mf * 16 + lg * 4 + r;
                float v = fmaxf(acc[mf][nf][r] + bv, 0.f);
                *(uint16_t*)(T + m * 128 +
                             (((nf * 16 + lr) * 2) ^ ((m & 7) << 4))) =
                    (uint16_t)bf16_rne(v);
              }
              acc[mf][nf] = f32x4{0.f, 0.f, 0.f, 0.f};
            }
#pragma unroll
          for (int kk = 0; kk < 2; kk++)
#pragma unroll
            for (int mf = 0; mf < 2; mf++) {
              int m = mf * 16 + lr;
              bf16x8 hv = *(const bf16x8*)(
                  T + m * 128 + ((kk * 64 + lg * 16) ^ ((m & 7) << 4)));
              u32x4 tv = *(u32x4*)&hv;
#pragma unroll
              for (int j = 0; j < 4; j++)
                asm("v_accvgpr_write_b32 %0, %1"
                    : "=a"(ha[so][kk][mf][j])
                    : "v"(tv[j]));
            }
        } else {  // bias+relu -> h1-LDS swizzled C-write (chunk j=so-4)
          uint8_t* H = smem + HOFF + (so - 4) * 32768;
#pragma unroll
          for (int mf = 0; mf < 2; mf++)
#pragma unroll
            for (int nf = 0; nf < 4; nf++) {
              float bv = b1s[so * 64 + nf * 16 + lr];
#pragma unroll
              for (int r = 0; r < 4; r++) {
                int row = w * 32 + mf * 16 + lg * 4 + r;
                float v = fmaxf(acc[mf][nf][r] + bv, 0.f);
                *(uint16_t*)(H + row * 128 +
                             (((nf * 2 + (lr >> 3)) ^ (row & 7)) << 4) +
                             (lr & 7) * 2) = (uint16_t)bf16_rne(v);
              }
              acc[mf][nf] = f32x4{0.f, 0.f, 0.f, 0.f};
            }
        }
      }
      const bool last = (t == 95);
      if (!last) writeB(g[(t + 1) % 3], (t + 1) & 1);
      if (t + 2 < 96) loadA((t + 2) % 12, a[t & 1]);
      if (t + 3 < 96) loadB(W1c, (t + 3) / 12, (t + 3) % 12, g[t % 3]);
      if (!last) ldsbar();
    }
  }

  // ============ layer 2 + fused layer 3: 8 chunks x 8 K-steps ============
  float s0[2][4], s1[2][4];
#pragma unroll
  for (int mf = 0; mf < 2; mf++)
#pragma unroll
    for (int r = 0; r < 4; r++) {
      s0[mf][r] = 0.f;
      s1[mf][r] = 0.f;
    }

  loadB(W2c, 0, 0, g[0]);
  loadB(W2c, 0, 1, g[1]);
  loadB(W2c, 0, 2, g[2]);
  writeB(g[0], 0);
  ldsbar();  // also publishes h1-LDS chunks

#pragma unroll
  for (int so = 0; so < 8; ++so) {
#pragma unroll
    for (int k = 0; k < 8; ++k) {
      const int t = so * 8 + k;
      {  // comp: A from AGPR (k<4) or h1-LDS (k>=4)
        const uint8_t* s = smem + (t & 1) * 8192;
#pragma unroll
        for (int kk = 0; kk < 2; ++kk) {
          bf16x8 b[4];
          compB(s, kk, b);
#pragma unroll
          for (int mf = 0; mf < 2; mf++) {
            bf16x8 av;
            if (k < 4) {
              uint32_t t0, t1, t2, t3;
              asm("v_accvgpr_read_b32 %0, %1" : "=v"(t0) : "a"(ha[k & 3][kk][mf][0]));
              asm("v_accvgpr_read_b32 %0, %1" : "=v"(t1) : "a"(ha[k & 3][kk][mf][1]));
              asm("v_accvgpr_read_b32 %0, %1" : "=v"(t2) : "a"(ha[k & 3][kk][mf][2]));
              asm("v_accvgpr_read_b32 %0, %1" : "=v"(t3) : "a"(ha[k & 3][kk][mf][3]));
              u32x4 tv = {t0, t1, t2, t3};
              av = *(bf16x8*)&tv;
            } else {
              int row = w * 32 + mf * 16 + lr;
              av = *(const bf16x8*)(smem + HOFF + (k - 4) * 32768 +
                                    row * 128 +
                                    (((kk * 4 + lg) ^ (row & 7)) << 4));
            }
#pragma unroll
            for (int nf = 0; nf < 4; nf++)
              acc[mf][nf] = __builtin_amdgcn_mfma_f32_16x16x32_bf16(
                  av, b[nf], acc[mf][nf], 0, 0, 0);
          }
        }
      }
      if (k == 7) {  // epilogue: bias+relu -> W3 dot accumulate
#pragma unroll
        for (int mf = 0; mf < 2; mf++)
#pragma unroll
          for (int nf = 0; nf < 4; nf++) {
            float bv = b2s[so * 64 + nf * 16 + lr];
            f32x2 wp = w3s[so * 64 + nf * 16 + lr];
#pragma unroll
            for (int r = 0; r < 4; r++) {
              float v = fmaxf(acc[mf][nf][r] + bv, 0.f);
              s0[mf][r] += v * wp[0];
              s1[mf][r] += v * wp[1];
            }
            acc[mf][nf] = f32x4{0.f, 0.f, 0.f, 0.f};
          }
      }
      const bool last = (t == 63);
      if (!last) writeB(g[(t + 1) % 3], (t + 1) & 1);
      if (t + 3 < 64) loadB(W2c, (t + 3) / 8, (t + 3) % 8, g[t % 3]);
      if (!last) ldsbar();
    }
  }

  // ---------------- final: shfl-reduce over 16 lanes, store ----------------
  f32x2 b3v = *(const f32x2*)(smem + 24576);
#pragma unroll
  for (int mf = 0; mf < 2; mf++)
#pragma unroll
    for (int r = 0; r < 4; r++) {
      float t0 = s0[mf][r], t1 = s1[mf][r];
#pragma unroll
      for (int d = 1; d < 16; d <<= 1) {
        t0 += __shfl_xor(t0, d);
        t1 += __shfl_xor(t1, d);
      }
      if (lr == 0) {
        int row = w * 32 + mf * 16 + lg * 4 + r;
        *(f32x2*)(out + ((size_t)row * 512 + c) * 2) =
            f32x2{t0 + b3v[0], t1 + b3v[1]};
      }
    }
}

extern "C" void kernel_launch(void* const* d_in, const int* in_sizes, int n_in,
                              void* d_out, int out_size, void* d_ws,
                              size_t ws_size, hipStream_t stream) {
  const float* x = (const float*)d_in[0];
  const float* W1 = (const float*)d_in[1];
  const float* b1 = (const float*)d_in[2];
  const float* W2 = (const float*)d_in[3];
  const float* b2 = (const float*)d_in[4];
  const float* W3 = (const float*)d_in[5];
  const float* b3 = (const float*)d_in[6];
  float* out = (float*)d_out;

  uint8_t* ws = (uint8_t*)d_ws;
  if (ws_size < 393216) return;
  uint32_t* xb = (uint32_t*)ws;

  cast_x_kernel<<<dim3(384), dim3(256), 0, stream>>>(x, xb, 98304);
  fused_mlp<<<dim3(512), dim3(512), 0, stream>>>(
      (const uint16_t*)xb, W1, b1, W2, b2, W3, b3, out);
}

// Round 10
// 422.999 us; speedup vs baseline: 1.3744x; 1.2732x over previous
//
#include <hip/hip_runtime.h>
#include <stdint.h>

typedef float f32x4 __attribute__((ext_vector_type(4)));
typedef float f32x2 __attribute__((ext_vector_type(2)));
typedef short bf16x8 __attribute__((ext_vector_type(8)));
typedef uint32_t u32x4 __attribute__((ext_vector_type(4)));

__device__ __forceinline__ uint32_t bf16_rne(float f) {
  uint32_t x = __float_as_uint(f);
  return (x + 0x7FFFu + ((x >> 16) & 1u)) >> 16;
}

// LDS-only barrier: waits this wave's DS ops, does NOT drain vmcnt.
__device__ __forceinline__ void ldsbar() {
  asm volatile("s_waitcnt lgkmcnt(0)\n\ts_barrier" ::: "memory");
}

// ---------------- kernel 0: cast x (f32) -> bf16 ----------------
__global__ void cast_x_kernel(const float* __restrict__ x,
                              uint32_t* __restrict__ xb, int n2) {
  int i = blockIdx.x * 256 + threadIdx.x;
  if (i >= n2) return;
  f32x2 v = *(const f32x2*)(x + 2 * i);
  xb[i] = bf16_rne(v[0]) | (bf16_rne(v[1]) << 16);
}

// ---------------- per-class GEMM, weights-once, R5-proven schedule --------
// Block: M=256 x N=64 of one class, BK=64, 8 waves (8M x 1N), acc[2][4].
// Live set in main loop ~100 VGPR (cap 128 at (512,2)): bias/W3 loaded ONLY
// in the epilogue (post-loop vmcnt drain is harmless), W-rotation 3-deep.
// A: MODE 0 = x bf16 rows (L2-resident); MODE 1 = h1 in FRAG-BLOCKED layout
//    (direct per-lane 16B loads, no repack). 2-phase lead.
// B: W f32 -> v_cvt_pk_bf16 -> swizzled ds_write_b128, dbuf; lgkm barriers.
// Epilogue MODE 0: bias+relu -> wave-private T-bounce -> frag-blocked h1
// store (16B/lane coalesced). MODE 1: bias+relu -> W3 dot -> shfl -> part.
// h1 frag layout: h1f[c][t2][kk][w][mf][lane][8bf16]
//   elem off = c*131072 + t2*16384 + kk*8192 + w*1024 + mf*512 + l*8
template <int K, int MODE>
__global__ __launch_bounds__(512, 2) void gemm_fused(
    const uint16_t* __restrict__ Abase, const float* __restrict__ Wbase,
    const float* __restrict__ biasBase, uint16_t* __restrict__ Hout,
    const float* __restrict__ W3base, float* __restrict__ part) {
  constexpr int NT = K / 64;
  __shared__ uint8_t smem[49152];  // 16K B-dbuf | 32K T-bounce (MODE0)

  const int tid = threadIdx.x;
  const int bid = blockIdx.x;
  // bijective XCD swizzle: class's 8 n-tile blocks land on one XCD
  const int logical = ((bid & 7) << 9) | (bid >> 3);
  const int c = logical >> 3;
  const int nt = logical & 7;
  const int n0 = nt * 64;

  const float* Wc = Wbase + (size_t)c * (K * 512) + n0;
  const int l = tid & 63, w = tid >> 6;
  const int lr = l & 15, lg = l >> 4;

  const uint16_t* Ap;
  if constexpr (MODE == 0)
    Ap = Abase + (size_t)(w * 32 + lr) * 768 + lg * 8;
  else
    Ap = Abase + (size_t)c * 131072 + w * 1024 + l * 8;

  f32x4 acc[2][4];
#pragma unroll
  for (int i = 0; i < 2; i++)
#pragma unroll
    for (int j = 0; j < 4; j++) acc[i][j] = {0.f, 0.f, 0.f, 0.f};

  auto loadB = [&](int ts, float* g) {
    const float* p = Wc + (size_t)(ts * 64 + w * 8) * 512 + l;
#pragma unroll
    for (int r = 0; r < 8; r++) g[r] = p[(size_t)r * 512];
  };
  auto loadA = [&](int ts, bf16x8* as) {
#pragma unroll
    for (int kk = 0; kk < 2; ++kk)
#pragma unroll
      for (int mf = 0; mf < 2; mf++) {
        if constexpr (MODE == 0)
          as[kk * 2 + mf] = *(const bf16x8*)(Ap + ts * 64 + kk * 32 +
                                             (size_t)mf * 16 * 768);
        else
          as[kk * 2 + mf] =
              *(const bf16x8*)(Ap + ts * 16384 + kk * 8192 + mf * 512);
      }
  };
  auto writeB = [&](const float* g, int buf) {
    uint32_t p0, p1, p2, p3;
    asm("v_cvt_pk_bf16_f32 %0, %1, %2" : "=v"(p0) : "v"(g[0]), "v"(g[1]));
    asm("v_cvt_pk_bf16_f32 %0, %1, %2" : "=v"(p1) : "v"(g[2]), "v"(g[3]));
    asm("v_cvt_pk_bf16_f32 %0, %1, %2" : "=v"(p2) : "v"(g[4]), "v"(g[5]));
    asm("v_cvt_pk_bf16_f32 %0, %1, %2" : "=v"(p3) : "v"(g[6]), "v"(g[7]));
    u32x4 p = {p0, p1, p2, p3};
    *(u32x4*)(smem + buf * 8192 + l * 128 + ((w ^ (l & 7)) << 4)) = p;
  };
  auto comp = [&](int buf, const bf16x8* as) {
    const uint8_t* s = smem + buf * 8192;
#pragma unroll
    for (int kk = 0; kk < 2; ++kk) {
      const int kx = ((lg * 16) ^ ((lr & 7) << 4)) ^ (kk << 6);
      bf16x8 b[4];
#pragma unroll
      for (int nf = 0; nf < 4; nf++)
        b[nf] = *(const bf16x8*)(s + (nf * 16 + lr) * 128 + kx);
#pragma unroll
      for (int mf = 0; mf < 2; mf++)
#pragma unroll
        for (int nf = 0; nf < 4; nf++)
          acc[mf][nf] = __builtin_amdgcn_mfma_f32_16x16x32_bf16(
              as[kk * 2 + mf], b[nf], acc[mf][nf], 0, 0, 0);
    }
  };

  float g[3][8];
  bf16x8 a[2][4];
  loadB(0, g[0]);
  loadB(1, g[1]);
  loadA(0, a[0]);
  loadB(2, g[2]);
  loadA(1, a[1]);
  writeB(g[0], 0);  // waits only B(0); A(0..1)/B(1..2) stay in flight
  ldsbar();

#pragma unroll
  for (int t = 0; t < NT; ++t) {
    comp(t & 1, a[t & 1]);                                // waits A(t)
    if (t + 1 < NT) writeB(g[(t + 1) % 3], (t + 1) & 1);  // wait already met
    if (t + 2 < NT) loadA(t + 2, a[t & 1]);               // 2 phases ahead
    if (t + 3 < NT) loadB(t + 3, g[t % 3]);               // 3 phases ahead
    if (t + 1 < NT) ldsbar();                             // publish buf
  }

  // -------- epilogue (post-loop global loads: drain is harmless now) ------
  float bv[4];
#pragma unroll
  for (int nf = 0; nf < 4; nf++)
    bv[nf] = biasBase[c * 512 + n0 + nf * 16 + lr];

  if constexpr (MODE == 0) {
    // bias+relu -> wave-private T-bounce -> frag-blocked coalesced store
    uint8_t* T = smem + 16384 + w * 4096;
#pragma unroll
    for (int mf = 0; mf < 2; mf++)
#pragma unroll
      for (int nf = 0; nf < 4; nf++)
#pragma unroll
        for (int r = 0; r < 4; r++) {
          int m = mf * 16 + lg * 4 + r;
          float v = fmaxf(acc[mf][nf][r] + bv[nf], 0.f);
          *(uint16_t*)(T + m * 128 + (((nf * 16 + lr) * 2) ^ ((m & 7) << 4))) =
              (uint16_t)bf16_rne(v);
        }
    uint16_t* Hc = Hout + (size_t)c * 131072 + nt * 16384 + w * 1024 + l * 8;
#pragma unroll
    for (int kk = 0; kk < 2; kk++)
#pragma unroll
      for (int mf = 0; mf < 2; mf++) {
        int m = mf * 16 + lr;
        bf16x8 hv = *(const bf16x8*)(T + m * 128 +
                                     ((kk * 64 + lg * 16) ^ ((m & 7) << 4)));
        *(bf16x8*)(Hc + kk * 8192 + mf * 512) = hv;
      }
  } else {
    float w30[4], w31[4];
#pragma unroll
    for (int nf = 0; nf < 4; nf++) {
      f32x2 t = *(const f32x2*)(W3base +
                                ((size_t)c * 512 + n0 + nf * 16 + lr) * 2);
      w30[nf] = t[0];
      w31[nf] = t[1];
    }
#pragma unroll
    for (int mf = 0; mf < 2; mf++)
#pragma unroll
      for (int r = 0; r < 4; r++) {
        float s0 = 0.f, s1 = 0.f;
#pragma unroll
        for (int nf = 0; nf < 4; nf++) {
          float v = fmaxf(acc[mf][nf][r] + bv[nf], 0.f);
          s0 += v * w30[nf];
          s1 += v * w31[nf];
        }
#pragma unroll
        for (int d = 1; d < 16; d <<= 1) {
          s0 += __shfl_xor(s0, d);
          s1 += __shfl_xor(s1, d);
        }
        if (lr == 0) {
          int m = w * 32 + mf * 16 + lg * 4 + r;
          *(f32x2*)(part + (((size_t)c * 256 + m) * 8 + nt) * 2) =
              f32x2{s0, s1};
        }
      }
  }
}

// ---------------- reduce partials -> out [B][C][2] ----------------
__global__ __launch_bounds__(512) void reduce_out(
    const float* __restrict__ part, const float* __restrict__ b3,
    float* __restrict__ out) {
  const int b = blockIdx.x, c = threadIdx.x;
  const f32x4* p = (const f32x4*)(part + ((size_t)c * 256 + b) * 16);
  f32x4 v0 = p[0], v1 = p[1], v2 = p[2], v3 = p[3];
  float s0 = b3[c * 2] + v0[0] + v0[2] + v1[0] + v1[2] + v2[0] + v2[2] +
             v3[0] + v3[2];
  float s1 = b3[c * 2 + 1] + v0[1] + v0[3] + v1[1] + v1[3] + v2[1] + v2[3] +
             v3[1] + v3[3];
  *(f32x2*)(out + ((size_t)b * 512 + c) * 2) = f32x2{s0, s1};
}

extern "C" void kernel_launch(void* const* d_in, const int* in_sizes, int n_in,
                              void* d_out, int out_size, void* d_ws,
                              size_t ws_size, hipStream_t stream) {
  const float* x = (const float*)d_in[0];
  const float* W1 = (const float*)d_in[1];
  const float* b1 = (const float*)d_in[2];
  const float* W2 = (const float*)d_in[3];
  const float* b2 = (const float*)d_in[4];
  const float* W3 = (const float*)d_in[5];
  const float* b3 = (const float*)d_in[6];
  float* out = (float*)d_out;

  uint8_t* ws = (uint8_t*)d_ws;
  const size_t xb_off = 0;
  const size_t h1_off = 393216;                // 256*768*2
  const size_t part_off = h1_off + 134217728;  // + 512*256*512*2
  const size_t need = part_off + 8388608;      // + 512*256*8*2*4
  if (ws_size < need) return;

  uint32_t* xb = (uint32_t*)(ws + xb_off);
  uint16_t* h1f = (uint16_t*)(ws + h1_off);
  float* part = (float*)(ws + part_off);

  cast_x_kernel<<<dim3(384), dim3(256), 0, stream>>>(x, xb, 98304);
  gemm_fused<768, 0><<<dim3(4096), dim3(512), 0, stream>>>(
      (const uint16_t*)xb, W1, b1, h1f, nullptr, nullptr);
  gemm_fused<512, 1><<<dim3(4096), dim3(512), 0, stream>>>(
      h1f, W2, b2, nullptr, W3, part);
  reduce_out<<<dim3(256), dim3(512), 0, stream>>>(part, b3, out);
}